// Round 5
// baseline (526.843 us; speedup 1.0000x reference)
//
#include <hip/hip_runtime.h>
#include <hip/hip_bf16.h>
#include <math.h>

#define S_ 4
#define N_ 4096
#define M_ 4096
#define D_ 128
#define NEG_ (-1e30f)
#define CH_ 4              // m-chunks per stem
#define MCH_ (M_ / CH_)    // 1024 m per chunk
#define LN2_ 0.69314718055994531f
#define LOG2E_ 1.44269504088896340f
#define NWORDS_ (S_ * N_ * (M_ / 16))   // 16-bit bitmask words = 4,194,304

typedef __bf16 bf16x8 __attribute__((ext_vector_type(8)));
typedef float f32x4 __attribute__((ext_vector_type(4)));

// RNE float -> bf16 bits
__device__ __forceinline__ unsigned short f2bf(float f) {
    unsigned u = __float_as_uint(f);
    unsigned r = (u + 0x7FFFu + ((u >> 16) & 1u)) >> 16;
    return (unsigned short)r;
}

// ---------------- Phase 1a: L2-normalize art AND ref rows, write bf16 ----------------
__global__ void nrm_rows_kernel(const float* __restrict__ art, const float* __restrict__ ref,
                                unsigned short* __restrict__ an, unsigned short* __restrict__ rn) {
    const int w = threadIdx.x >> 6;
    const int lane = threadIdx.x & 63;
    const int row = blockIdx.x * 4 + w;             // 0 .. S_*(N_+M_)-1
    const bool is_art = row < S_ * N_;
    const float* src = is_art ? (art + (size_t)row * D_)
                              : (ref + (size_t)(row - S_ * N_) * D_);
    unsigned short* dst = is_art ? (an + (size_t)row * D_)
                                 : (rn + (size_t)(row - S_ * N_) * D_);
    const float2 v = *reinterpret_cast<const float2*>(src + lane * 2);
    float ss = v.x * v.x + v.y * v.y;
#pragma unroll
    for (int off = 1; off < 64; off <<= 1) ss += __shfl_xor(ss, off);
    const float scale = 1.0f / fmaxf(sqrtf(ss), 1e-12f);
    unsigned pack = (unsigned)f2bf(v.x * scale) | ((unsigned)f2bf(v.y * scale) << 16);
    *reinterpret_cast<unsigned*>(dst + lane * 2) = pack;
}

// ---------------- Phase 1b: bitpack the mask (perfectly-coalesced streaming) ----------------
// int32 mask: 268 MB read once at BW roofline -> 8 MB of bits. byte mask: 67 MB.
// Bit j of 16-bit word i == (mask flat element i*16+j != 0). Little-endian u64 reads
// in the main kernel then give bit j == element (k*64+j).
__global__ __launch_bounds__(256) void bitpack_kernel(const unsigned* __restrict__ maskp,
                                                      unsigned short* __restrict__ bits) {
    // per-block mask dtype detection: byte-packed bools read as u32 show values > 1
    const unsigned probe = maskp[threadIdx.x & 63];
    const bool byte_mode = (__ballot(probe > 1u) != 0ull);
    const int stride = gridDim.x * 256;
    const int4* p = (const int4*)maskp;
    if (byte_mode) {
        for (int i = blockIdx.x * 256 + threadIdx.x; i < NWORDS_; i += stride) {
            const int4 q = p[i];   // 16 bool bytes
            unsigned v =  ((unsigned)q.x & 1u)         | ((((unsigned)q.x >> 8) & 1u) << 1)
                       | ((((unsigned)q.x >> 16) & 1u) << 2) | ((((unsigned)q.x >> 24) & 1u) << 3)
                       | (((unsigned)q.y & 1u) << 4)   | ((((unsigned)q.y >> 8) & 1u) << 5)
                       | ((((unsigned)q.y >> 16) & 1u) << 6) | ((((unsigned)q.y >> 24) & 1u) << 7)
                       | (((unsigned)q.z & 1u) << 8)   | ((((unsigned)q.z >> 8) & 1u) << 9)
                       | ((((unsigned)q.z >> 16) & 1u) << 10) | ((((unsigned)q.z >> 24) & 1u) << 11)
                       | (((unsigned)q.w & 1u) << 12)  | ((((unsigned)q.w >> 8) & 1u) << 13)
                       | ((((unsigned)q.w >> 16) & 1u) << 14) | ((((unsigned)q.w >> 24) & 1u) << 15);
            bits[i] = (unsigned short)v;
        }
    } else {
        for (int i = blockIdx.x * 256 + threadIdx.x; i < NWORDS_; i += stride) {
            const int4 a = p[i * 4 + 0], b = p[i * 4 + 1], c = p[i * 4 + 2], d = p[i * 4 + 3];
            unsigned v =  ((unsigned)a.x & 1u)        | (((unsigned)a.y & 1u) << 1)
                       | (((unsigned)a.z & 1u) << 2)  | (((unsigned)a.w & 1u) << 3)
                       | (((unsigned)b.x & 1u) << 4)  | (((unsigned)b.y & 1u) << 5)
                       | (((unsigned)b.z & 1u) << 6)  | (((unsigned)b.w & 1u) << 7)
                       | (((unsigned)c.x & 1u) << 8)  | (((unsigned)c.y & 1u) << 9)
                       | (((unsigned)c.z & 1u) << 10) | (((unsigned)c.w & 1u) << 11)
                       | (((unsigned)d.x & 1u) << 12) | (((unsigned)d.y & 1u) << 13)
                       | (((unsigned)d.z & 1u) << 14) | (((unsigned)d.w & 1u) << 15);
            bits[i] = (unsigned short)v;
        }
    }
}

// ---------------- Phase 2: fused GEMM + masked/unmasked online logsumexp ----------------
// grid 2048 blocks (CH_ x S_ x 128 n-blocks), 256 threads. XCD-bijective swizzle.
// wave w: n-subtile = w&1, m-sub = w>>1. Transposed MFMA: lane owns 1 anchor col, 4 m rows.
// Mask arrives as 1 u64 bit-word per lane per 64-m iteration (L2-resident, 8 MB total).
__global__ __launch_bounds__(256, 8) void infonce_main_kernel(
    const unsigned short* __restrict__ an, const unsigned short* __restrict__ rn,
    const unsigned long long* __restrict__ bits64, const float* __restrict__ logtemp,
    float4* __restrict__ part4) {

    const int bid = blockIdx.x;
    const int swz = (bid & 7) * 256 + (bid >> 3);   // 2048 % 8 == 0 -> bijective
    const int ch = swz >> 9;
    const int s = (swz >> 7) & 3;
    const int nblk = swz & 127;
    const int n_base = nblk * 32;

    const int tid = threadIdx.x;
    const int w = tid >> 6;
    const int lane = tid & 63;
    const int nsub = w & 1;
    const int msub = w >> 1;
    const int n16 = n_base + nsub * 16;
    const int lrow = lane & 15;        // anchor col within 16-group
    const int lgrp = lane >> 4;        // k-group / output row group
    const float scale2 = __expf(-logtemp[0]) * LOG2E_;   // 1/(temp*ln2)

    // art fragments resident in registers
    bf16x8 bfr[4];
    const unsigned short* abase = an + ((size_t)(s * N_ + n16 + lrow)) * D_ + lgrp * 8;
#pragma unroll
    for (int kc = 0; kc < 4; ++kc)
        bfr[kc] = *reinterpret_cast<const bf16x8*>(abase + kc * 32);

    const int m_begin = ch * MCH_ + msub * (MCH_ / 2);
    const unsigned short* rbase = rn + ((size_t)(s * M_ + m_begin + lrow)) * D_ + lgrp * 8;
    const unsigned long long* brow =
        bits64 + (size_t)(s * N_ + n16 + lrow) * (M_ / 64) + (m_begin >> 6);

    float dmax = NEG_, dsum = 0.f, nsum = 0.f;
    int npos = 0;

#pragma unroll 2
    for (int it = 0; it < (MCH_ / 2) / 64; ++it) {   // 8 iterations x 64 m
        const unsigned long long w64 = brow[it];     // this lane's 64 mask bits (L2)
        // ---- 4 independent MFMA chains ----
        f32x4 acc0 = {0.f, 0.f, 0.f, 0.f}, acc1 = {0.f, 0.f, 0.f, 0.f};
        f32x4 acc2 = {0.f, 0.f, 0.f, 0.f}, acc3 = {0.f, 0.f, 0.f, 0.f};
        const unsigned short* rp = rbase + (size_t)it * 64 * D_;
#pragma unroll
        for (int kc = 0; kc < 4; ++kc) {
            acc0 = __builtin_amdgcn_mfma_f32_16x16x32_bf16(
                *reinterpret_cast<const bf16x8*>(rp + 0 * 16 * D_ + kc * 32), bfr[kc], acc0, 0, 0, 0);
            acc1 = __builtin_amdgcn_mfma_f32_16x16x32_bf16(
                *reinterpret_cast<const bf16x8*>(rp + 1 * 16 * D_ + kc * 32), bfr[kc], acc1, 0, 0, 0);
            acc2 = __builtin_amdgcn_mfma_f32_16x16x32_bf16(
                *reinterpret_cast<const bf16x8*>(rp + 2 * 16 * D_ + kc * 32), bfr[kc], acc2, 0, 0, 0);
            acc3 = __builtin_amdgcn_mfma_f32_16x16x32_bf16(
                *reinterpret_cast<const bf16x8*>(rp + 3 * 16 * D_ + kc * 32), bfr[kc], acc3, 0, 0, 0);
        }
        // ---- extract this lane's 16 mask bits (m = t*16 + lgrp*4 + i) ----
        const unsigned long long v = w64 >> (lgrp * 4);
        const unsigned nib0 = (unsigned)v & 0xFu;
        const unsigned nib1 = (unsigned)(v >> 16) & 0xFu;
        const unsigned nib2 = (unsigned)(v >> 32) & 0xFu;
        const unsigned nib3 = (unsigned)(v >> 48) & 0xFu;
        npos += __popc(nib0 | (nib1 << 4) | (nib2 << 8) | (nib3 << 12));
        // ---- base-2 logits ----
        float l[16];
#pragma unroll
        for (int i = 0; i < 4; ++i) {
            l[i]      = acc0[i] * scale2;  l[4 + i]  = acc1[i] * scale2;
            l[8 + i]  = acc2[i] * scale2;  l[12 + i] = acc3[i] * scale2;
        }
        float a0 = fmaxf(l[0], l[1]),  a1 = fmaxf(l[2], l[3]);
        float a2 = fmaxf(l[4], l[5]),  a3 = fmaxf(l[6], l[7]);
        float a4 = fmaxf(l[8], l[9]),  a5 = fmaxf(l[10], l[11]);
        float a6 = fmaxf(l[12], l[13]), a7 = fmaxf(l[14], l[15]);
        float tmax = fmaxf(fmaxf(fmaxf(a0, a1), fmaxf(a2, a3)),
                           fmaxf(fmaxf(a4, a5), fmaxf(a6, a7)));
        const float nmx = fmaxf(dmax, tmax);
        const float r = exp2f(dmax - nmx);
        float e[16];
#pragma unroll
        for (int i = 0; i < 16; ++i) e[i] = exp2f(l[i] - nmx);
        float s0 = (e[0] + e[1]) + (e[2] + e[3]),   s1 = (e[4] + e[5]) + (e[6] + e[7]);
        float s2 = (e[8] + e[9]) + (e[10] + e[11]), s3 = (e[12] + e[13]) + (e[14] + e[15]);
        dsum = dsum * r + ((s0 + s1) + (s2 + s3));
        // num: per-bit select then sum tree
        float p0 = ((nib0 & 1u)      ? e[0]  : 0.f) + (((nib0 >> 1) & 1u) ? e[1]  : 0.f)
                 + (((nib0 >> 2) & 1u) ? e[2]  : 0.f) + (((nib0 >> 3) & 1u) ? e[3]  : 0.f);
        float p1 = ((nib1 & 1u)      ? e[4]  : 0.f) + (((nib1 >> 1) & 1u) ? e[5]  : 0.f)
                 + (((nib1 >> 2) & 1u) ? e[6]  : 0.f) + (((nib1 >> 3) & 1u) ? e[7]  : 0.f);
        float p2 = ((nib2 & 1u)      ? e[8]  : 0.f) + (((nib2 >> 1) & 1u) ? e[9]  : 0.f)
                 + (((nib2 >> 2) & 1u) ? e[10] : 0.f) + (((nib2 >> 3) & 1u) ? e[11] : 0.f);
        float p3 = ((nib3 & 1u)      ? e[12] : 0.f) + (((nib3 >> 1) & 1u) ? e[13] : 0.f)
                 + (((nib3 >> 2) & 1u) ? e[14] : 0.f) + (((nib3 >> 3) & 1u) ? e[15] : 0.f);
        nsum = nsum * r + ((p0 + p1) + (p2 + p3));
        dmax = nmx;
    }

    float npf = (float)npos;
    // merge the 4 lane-groups (same anchor, different m): xor 16, 32
#pragma unroll
    for (int off = 16; off < 64; off <<= 1) {
        float odm = __shfl_xor(dmax, off), ods = __shfl_xor(dsum, off);
        float ons = __shfl_xor(nsum, off), onp = __shfl_xor(npf, off);
        float nm = fmaxf(dmax, odm);
        float ra = exp2f(dmax - nm), rb = exp2f(odm - nm);
        dsum = dsum * ra + ods * rb;
        nsum = nsum * ra + ons * rb;
        npf += onp;
        dmax = nm;
    }

    __shared__ float4 lds4[4][16];
    if (lane < 16) lds4[w][lane] = make_float4(dmax, dsum, nsum, npf);
    __syncthreads();

    // merge msub halves (waves {0,2},{1,3}); write (anchor, chunk) partial
    if (w == 0 && lane < 32) {
        const int wsub = lane >> 4;
        const int ni = lane & 15;
        const float4 A = lds4[wsub][ni];
        const float4 B = lds4[wsub + 2][ni];
        const float nm = fmaxf(A.x, B.x);
        const float ra = exp2f(A.x - nm), rb = exp2f(B.x - nm);
        const float ds = A.y * ra + B.y * rb;
        const float ns = A.z * ra + B.z * rb;
        const float np = A.w + B.w;
        const int ag = s * N_ + n_base + wsub * 16 + ni;
        part4[ag * CH_ + ch] = make_float4(nm, ds, ns, np);
    }
}

// ---------------- Phase 3: merge chunk partials -> per-block (pa,cnt) partial ----------------
__global__ void reduce_kernel(const float4* __restrict__ part4, float2* __restrict__ bpart) {
    const int a = blockIdx.x * 256 + threadIdx.x;   // anchor
    const int w = threadIdx.x >> 6;
    const int lane = threadIdx.x & 63;
    float dm = NEG_, ds = 0.f, ns = 0.f, npf = 0.f;
#pragma unroll
    for (int ch = 0; ch < CH_; ++ch) {
        const float4 p = part4[a * CH_ + ch];
        const float m2 = fmaxf(dm, p.x);
        const float ra = exp2f(dm - m2), rb = exp2f(p.x - m2);
        ds = ds * ra + p.y * rb;
        ns = ns * ra + p.z * rb;
        npf += p.w;
        dm = m2;
    }
    const bool valid = (npf > 0.5f) && (npf < (float)M_ - 0.5f);
    float pa = valid ? LN2_ * (log2f(ds) - log2f(ns)) : 0.f;
    float cv = valid ? 1.f : 0.f;
#pragma unroll
    for (int off = 1; off < 64; off <<= 1) {
        pa += __shfl_xor(pa, off);
        cv += __shfl_xor(cv, off);
    }
    __shared__ float sp[4], sc[4];
    if (lane == 0) { sp[w] = pa; sc[w] = cv; }
    __syncthreads();
    if (threadIdx.x == 0)
        bpart[blockIdx.x] = make_float2(sp[0] + sp[1] + sp[2] + sp[3],
                                        sc[0] + sc[1] + sc[2] + sc[3]);
}

// ---------------- Phase 4: finalize (64 block-partials, 16 per stem) ----------------
__global__ void finalize_kernel(const float2* __restrict__ bpart, float* __restrict__ out) {
    const int t = threadIdx.x;   // 64 threads
    const float2 v = bpart[t];
    float pa = v.x, cv = v.y;
#pragma unroll
    for (int off = 1; off < 16; off <<= 1) {
        pa += __shfl_xor(pa, off);
        cv += __shfl_xor(cv, off);
    }
    const float p0 = __shfl(pa, 0),  c0 = __shfl(cv, 0);
    const float p1 = __shfl(pa, 16), c1 = __shfl(cv, 16);
    const float p2 = __shfl(pa, 32), c2 = __shfl(cv, 32);
    const float p3 = __shfl(pa, 48), c3 = __shfl(cv, 48);
    if (t == 0) {
        float total = 0.f;
        int scnt = 0;
        const float ps[4] = {p0, p1, p2, p3};
        const float cs[4] = {c0, c1, c2, c3};
        for (int s = 0; s < S_; ++s) {
            const float stem = ps[s] / fmaxf(cs[s], 1.f);
            if (cs[s] > 0.f) { total += stem; scnt++; }
        }
        out[0] = total / (float)(scnt > 0 ? scnt : 1);
    }
}

extern "C" void kernel_launch(void* const* d_in, const int* in_sizes, int n_in,
                              void* d_out, int out_size, void* d_ws, size_t ws_size,
                              hipStream_t stream) {
    const float* art = (const float*)d_in[0];
    const float* ref = (const float*)d_in[1];
    const void* mask = d_in[2];
    const float* lt = (const float*)d_in[3];
    float* out = (float*)d_out;

    char* ws = (char*)d_ws;
    unsigned short* an = (unsigned short*)ws;                       // 4 MB
    unsigned short* rn = (unsigned short*)(ws + (size_t)4194304);   // 4 MB
    unsigned short* bits = (unsigned short*)(ws + (size_t)8388608); // 8 MB bitmask
    float4* part4 = (float4*)(ws + (size_t)16777216);               // 1 MB
    float2* bpart = (float2*)(ws + (size_t)17825792);               // 512 B

    nrm_rows_kernel<<<(S_ * (N_ + M_)) / 4, 256, 0, stream>>>(art, ref, an, rn);
    bitpack_kernel<<<4096, 256, 0, stream>>>((const unsigned*)mask, bits);
    infonce_main_kernel<<<S_ * (N_ / 32) * CH_, 256, 0, stream>>>(
        an, rn, (const unsigned long long*)bits, lt, part4);
    reduce_kernel<<<(S_ * N_) / 256, 256, 0, stream>>>(part4, bpart);
    finalize_kernel<<<1, 64, 0, stream>>>(bpart, out);
}

// Round 6
// 430.325 us; speedup vs baseline: 1.2243x; 1.2243x over previous
//
#include <hip/hip_runtime.h>
#include <hip/hip_bf16.h>
#include <math.h>

#define S_ 4
#define N_ 4096
#define M_ 4096
#define D_ 128
#define NEG_ (-1e30f)
#define CH_ 2              // m-chunks per stem
#define MCH_ (M_ / CH_)    // 2048 m per chunk
#define NST_ (MCH_ / 64)   // 32 stages of 64 m
#define LN2_ 0.69314718055994531f
#define LOG2E_ 1.44269504088896340f
#define NWORDS_ (S_ * N_ * (M_ / 16))   // 16-bit bitmask words

typedef __bf16 bf16x8 __attribute__((ext_vector_type(8)));
typedef float f32x4 __attribute__((ext_vector_type(4)));

// async global->LDS, 16B per lane (dest = wave-uniform base + lane*16)
__device__ __forceinline__ void gll16(const void* g, void* l) {
    __builtin_amdgcn_global_load_lds(
        (const __attribute__((address_space(1))) unsigned int*)g,
        (__attribute__((address_space(3))) unsigned int*)l, 16, 0, 0);
}

// RNE float -> bf16 bits
__device__ __forceinline__ unsigned short f2bf(float f) {
    unsigned u = __float_as_uint(f);
    unsigned r = (u + 0x7FFFu + ((u >> 16) & 1u)) >> 16;
    return (unsigned short)r;
}

// ---------------- Phase 1a: L2-normalize art AND ref rows, write bf16 ----------------
__global__ void nrm_rows_kernel(const float* __restrict__ art, const float* __restrict__ ref,
                                unsigned short* __restrict__ an, unsigned short* __restrict__ rn) {
    const int w = threadIdx.x >> 6;
    const int lane = threadIdx.x & 63;
    const int row = blockIdx.x * 4 + w;             // 0 .. S_*(N_+M_)-1
    const bool is_art = row < S_ * N_;
    const float* src = is_art ? (art + (size_t)row * D_)
                              : (ref + (size_t)(row - S_ * N_) * D_);
    unsigned short* dst = is_art ? (an + (size_t)row * D_)
                                 : (rn + (size_t)(row - S_ * N_) * D_);
    const float2 v = *reinterpret_cast<const float2*>(src + lane * 2);
    float ss = v.x * v.x + v.y * v.y;
#pragma unroll
    for (int off = 1; off < 64; off <<= 1) ss += __shfl_xor(ss, off);
    const float scale = 1.0f / fmaxf(sqrtf(ss), 1e-12f);
    unsigned pack = (unsigned)f2bf(v.x * scale) | ((unsigned)f2bf(v.y * scale) << 16);
    *reinterpret_cast<unsigned*>(dst + lane * 2) = pack;
}

// ---------------- Phase 1b: bitpack the mask (coalesced streaming) ----------------
__global__ __launch_bounds__(256) void bitpack_kernel(const unsigned* __restrict__ maskp,
                                                      unsigned short* __restrict__ bits) {
    const unsigned probe = maskp[threadIdx.x & 63];
    const bool byte_mode = (__ballot(probe > 1u) != 0ull);
    const int stride = gridDim.x * 256;
    const int4* p = (const int4*)maskp;
    if (byte_mode) {
        for (int i = blockIdx.x * 256 + threadIdx.x; i < NWORDS_; i += stride) {
            const int4 q = p[i];   // 16 bool bytes
            unsigned v =  ((unsigned)q.x & 1u)         | ((((unsigned)q.x >> 8) & 1u) << 1)
                       | ((((unsigned)q.x >> 16) & 1u) << 2) | ((((unsigned)q.x >> 24) & 1u) << 3)
                       | (((unsigned)q.y & 1u) << 4)   | ((((unsigned)q.y >> 8) & 1u) << 5)
                       | ((((unsigned)q.y >> 16) & 1u) << 6) | ((((unsigned)q.y >> 24) & 1u) << 7)
                       | (((unsigned)q.z & 1u) << 8)   | ((((unsigned)q.z >> 8) & 1u) << 9)
                       | ((((unsigned)q.z >> 16) & 1u) << 10) | ((((unsigned)q.z >> 24) & 1u) << 11)
                       | (((unsigned)q.w & 1u) << 12)  | ((((unsigned)q.w >> 8) & 1u) << 13)
                       | ((((unsigned)q.w >> 16) & 1u) << 14) | ((((unsigned)q.w >> 24) & 1u) << 15);
            bits[i] = (unsigned short)v;
        }
    } else {
        for (int i = blockIdx.x * 256 + threadIdx.x; i < NWORDS_; i += stride) {
            const int4 a = p[i * 4 + 0], b = p[i * 4 + 1], c = p[i * 4 + 2], d = p[i * 4 + 3];
            unsigned v =  ((unsigned)a.x & 1u)        | (((unsigned)a.y & 1u) << 1)
                       | (((unsigned)a.z & 1u) << 2)  | (((unsigned)a.w & 1u) << 3)
                       | (((unsigned)b.x & 1u) << 4)  | (((unsigned)b.y & 1u) << 5)
                       | (((unsigned)b.z & 1u) << 6)  | (((unsigned)b.w & 1u) << 7)
                       | (((unsigned)c.x & 1u) << 8)  | (((unsigned)c.y & 1u) << 9)
                       | (((unsigned)c.z & 1u) << 10) | (((unsigned)c.w & 1u) << 11)
                       | (((unsigned)d.x & 1u) << 12) | (((unsigned)d.y & 1u) << 13)
                       | (((unsigned)d.z & 1u) << 14) | (((unsigned)d.w & 1u) << 15);
            bits[i] = (unsigned short)v;
        }
    }
}

// ---------------- Phase 2: LDS-staged GEMM + fused online logsumexp ----------------
// 1024 blocks (CH_ x S_ x 128 n-blocks) x 4 waves = 1 generation at 4 blocks/CU.
// Block: 32 anchors x 2048 m. Stage: 64 m rows (16 KB) in LDS, double-buffered,
// filled by global_load_lds dwordx4 with XOR chunk-swizzle applied on the GLOBAL
// source address (LDS dest stays linear); ds_read_b128 applies the same swizzle.
// Wave w: nsub=w&1 (16 anchors), msub=w>>1 (32 of the 64 staged rows = 2 MFMA tiles).
__global__ __launch_bounds__(256, 4) void infonce_main_kernel(
    const unsigned short* __restrict__ an, const unsigned short* __restrict__ rn,
    const unsigned* __restrict__ bits32, const float* __restrict__ logtemp,
    float4* __restrict__ part4) {

    const int bid = blockIdx.x;
    const int swz = (bid & 7) * 128 + (bid >> 3);   // 1024 % 8 == 0 -> bijective
    const int ch = swz >> 9;                        // 0..1
    const int s = (swz >> 7) & 3;                   // 0..3
    const int nblk = swz & 127;                     // 0..127
    const int n_base = nblk * 32;

    const int tid = threadIdx.x;
    const int w = tid >> 6;
    const int lane = tid & 63;
    const int nsub = w & 1;
    const int msub = w >> 1;
    const int n16 = n_base + nsub * 16;
    const int lrow = lane & 15;        // anchor col within 16-group
    const int lgrp = lane >> 4;        // k-group / m-row group
    const float scale2 = __expf(-logtemp[0]) * LOG2E_;   // 1/(temp*ln2)

    __shared__ unsigned char smem[2][64 * 256];   // 2 x 16 KB rn stage buffers
    __shared__ float4 lds4[4][16];

    // anchor fragments resident in registers
    bf16x8 bfr[4];
    const unsigned short* abase = an + ((size_t)(s * N_ + n16 + lrow)) * D_ + lgrp * 8;
#pragma unroll
    for (int kc = 0; kc < 4; ++kc)
        bfr[kc] = *reinterpret_cast<const bf16x8*>(abase + kc * 32);

    // staging: thread covers row srow (+j*16), 16B chunk (lane&15), source chunk XOR-swizzled
    const int srow = w * 4 + (lane >> 4);                         // 0..15
    const int schunk = (lane & 15) ^ (srow & 7);
    const int lane_src_off = srow * 256 + schunk * 16;
    const unsigned char* rn_chunk =
        (const unsigned char*)(rn + ((size_t)(s * M_ + ch * MCH_)) * D_);

    // per-lane bitmask row pointer: one u32 per stage (32 m bits)
    const unsigned* bw = bits32 + (size_t)(s * N_ + n16 + lrow) * (M_ / 32) + ch * (MCH_ / 32) + msub;

    // ds_read addressing: row = msub*32 + t*16 + lrow, chunk = (kc*4+lgrp) ^ (lrow&7)
    const int rb0 = (msub * 32 + lrow) * 256;
    int coff[4];
#pragma unroll
    for (int kc = 0; kc < 4; ++kc) coff[kc] = ((kc * 4 + lgrp) ^ (lrow & 7)) * 16;

    float dmax = NEG_, dsum = 0.f, nsum = 0.f;
    int npos = 0;

    // prologue: stage 0
    {
        const unsigned char* src = rn_chunk + lane_src_off;
        unsigned char* dst = &smem[0][w * 1024];
#pragma unroll
        for (int j = 0; j < 4; ++j) gll16(src + j * 4096, dst + j * 4096);
    }
    __syncthreads();

    for (int st = 0; st < NST_; ++st) {
        const int nb = st & 1;
        if (st + 1 < NST_) {   // prefetch next stage into other buffer
            const unsigned char* src = rn_chunk + (size_t)(st + 1) * 16384 + lane_src_off;
            unsigned char* dst = &smem[nb ^ 1][w * 1024];
#pragma unroll
            for (int j = 0; j < 4; ++j) gll16(src + j * 4096, dst + j * 4096);
        }
        const unsigned w32 = bw[st * 2];           // L2-resident mask bits
        const unsigned char* base = &smem[nb][0] + rb0;
        f32x4 acc0 = {0.f, 0.f, 0.f, 0.f}, acc1 = {0.f, 0.f, 0.f, 0.f};
#pragma unroll
        for (int kc = 0; kc < 4; ++kc) {
            acc0 = __builtin_amdgcn_mfma_f32_16x16x32_bf16(
                *reinterpret_cast<const bf16x8*>(base + coff[kc]), bfr[kc], acc0, 0, 0, 0);
            acc1 = __builtin_amdgcn_mfma_f32_16x16x32_bf16(
                *reinterpret_cast<const bf16x8*>(base + 4096 + coff[kc]), bfr[kc], acc1, 0, 0, 0);
        }
        // ---- epilogue: 8 logits (2 tiles x 4 m) ----
        float l0 = acc0[0] * scale2, l1 = acc0[1] * scale2, l2 = acc0[2] * scale2, l3 = acc0[3] * scale2;
        float l4 = acc1[0] * scale2, l5 = acc1[1] * scale2, l6 = acc1[2] * scale2, l7 = acc1[3] * scale2;
        float tmax = fmaxf(fmaxf(fmaxf(l0, l1), fmaxf(l2, l3)),
                           fmaxf(fmaxf(l4, l5), fmaxf(l6, l7)));
        const float nmx = fmaxf(dmax, tmax);
        const float r = exp2f(dmax - nmx);
        float e0 = exp2f(l0 - nmx), e1 = exp2f(l1 - nmx), e2 = exp2f(l2 - nmx), e3 = exp2f(l3 - nmx);
        float e4 = exp2f(l4 - nmx), e5 = exp2f(l5 - nmx), e6 = exp2f(l6 - nmx), e7 = exp2f(l7 - nmx);
        dsum = dsum * r + (((e0 + e1) + (e2 + e3)) + ((e4 + e5) + (e6 + e7)));
        const unsigned nib0 = (w32 >> (lgrp * 4)) & 0xFu;         // tile 0 bits
        const unsigned nib1 = (w32 >> (16 + lgrp * 4)) & 0xFu;    // tile 1 bits
        float p0 = ((nib0 & 1u) ? e0 : 0.f) + (((nib0 >> 1) & 1u) ? e1 : 0.f);
        float p1 = (((nib0 >> 2) & 1u) ? e2 : 0.f) + (((nib0 >> 3) & 1u) ? e3 : 0.f);
        float p2 = ((nib1 & 1u) ? e4 : 0.f) + (((nib1 >> 1) & 1u) ? e5 : 0.f);
        float p3 = (((nib1 >> 2) & 1u) ? e6 : 0.f) + (((nib1 >> 3) & 1u) ? e7 : 0.f);
        nsum = nsum * r + ((p0 + p1) + (p2 + p3));
        npos += __popc(nib0 | (nib1 << 4));
        dmax = nmx;
        __syncthreads();
    }

    float npf = (float)npos;
    // merge the 4 lane-groups (same anchor, different m): xor 16, 32
#pragma unroll
    for (int off = 16; off < 64; off <<= 1) {
        float odm = __shfl_xor(dmax, off), ods = __shfl_xor(dsum, off);
        float ons = __shfl_xor(nsum, off), onp = __shfl_xor(npf, off);
        float nm = fmaxf(dmax, odm);
        float ra = exp2f(dmax - nm), rb = exp2f(odm - nm);
        dsum = dsum * ra + ods * rb;
        nsum = nsum * ra + ons * rb;
        npf += onp;
        dmax = nm;
    }

    if (lane < 16) lds4[w][lane] = make_float4(dmax, dsum, nsum, npf);
    __syncthreads();

    // merge msub halves (waves {0,2},{1,3}); write (anchor, chunk) partial
    if (w == 0 && lane < 32) {
        const int wsub = lane >> 4;
        const int ni = lane & 15;
        const float4 A = lds4[wsub][ni];
        const float4 B = lds4[wsub + 2][ni];
        const float nm = fmaxf(A.x, B.x);
        const float ra = exp2f(A.x - nm), rb = exp2f(B.x - nm);
        const float ds = A.y * ra + B.y * rb;
        const float ns = A.z * ra + B.z * rb;
        const float np = A.w + B.w;
        const int ag = s * N_ + n_base + wsub * 16 + ni;
        part4[ag * CH_ + ch] = make_float4(nm, ds, ns, np);
    }
}

// ---------------- Phase 3: merge chunk partials -> per-block (pa,cnt) partial ----------------
__global__ void reduce_kernel(const float4* __restrict__ part4, float2* __restrict__ bpart) {
    const int a = blockIdx.x * 256 + threadIdx.x;   // anchor
    const int w = threadIdx.x >> 6;
    const int lane = threadIdx.x & 63;
    float dm = NEG_, ds = 0.f, ns = 0.f, npf = 0.f;
#pragma unroll
    for (int ch = 0; ch < CH_; ++ch) {
        const float4 p = part4[a * CH_ + ch];
        const float m2 = fmaxf(dm, p.x);
        const float ra = exp2f(dm - m2), rb = exp2f(p.x - m2);
        ds = ds * ra + p.y * rb;
        ns = ns * ra + p.z * rb;
        npf += p.w;
        dm = m2;
    }
    const bool valid = (npf > 0.5f) && (npf < (float)M_ - 0.5f);
    float pa = valid ? LN2_ * (log2f(ds) - log2f(ns)) : 0.f;
    float cv = valid ? 1.f : 0.f;
#pragma unroll
    for (int off = 1; off < 64; off <<= 1) {
        pa += __shfl_xor(pa, off);
        cv += __shfl_xor(cv, off);
    }
    __shared__ float sp[4], sc[4];
    if (lane == 0) { sp[w] = pa; sc[w] = cv; }
    __syncthreads();
    if (threadIdx.x == 0)
        bpart[blockIdx.x] = make_float2(sp[0] + sp[1] + sp[2] + sp[3],
                                        sc[0] + sc[1] + sc[2] + sc[3]);
}

// ---------------- Phase 4: finalize (64 block-partials, 16 per stem) ----------------
__global__ void finalize_kernel(const float2* __restrict__ bpart, float* __restrict__ out) {
    const int t = threadIdx.x;   // 64 threads
    const float2 v = bpart[t];
    float pa = v.x, cv = v.y;
#pragma unroll
    for (int off = 1; off < 16; off <<= 1) {
        pa += __shfl_xor(pa, off);
        cv += __shfl_xor(cv, off);
    }
    const float p0 = __shfl(pa, 0),  c0 = __shfl(cv, 0);
    const float p1 = __shfl(pa, 16), c1 = __shfl(cv, 16);
    const float p2 = __shfl(pa, 32), c2 = __shfl(cv, 32);
    const float p3 = __shfl(pa, 48), c3 = __shfl(cv, 48);
    if (t == 0) {
        float total = 0.f;
        int scnt = 0;
        const float ps[4] = {p0, p1, p2, p3};
        const float cs[4] = {c0, c1, c2, c3};
        for (int s = 0; s < S_; ++s) {
            const float stem = ps[s] / fmaxf(cs[s], 1.f);
            if (cs[s] > 0.f) { total += stem; scnt++; }
        }
        out[0] = total / (float)(scnt > 0 ? scnt : 1);
    }
}

extern "C" void kernel_launch(void* const* d_in, const int* in_sizes, int n_in,
                              void* d_out, int out_size, void* d_ws, size_t ws_size,
                              hipStream_t stream) {
    const float* art = (const float*)d_in[0];
    const float* ref = (const float*)d_in[1];
    const void* mask = d_in[2];
    const float* lt = (const float*)d_in[3];
    float* out = (float*)d_out;

    char* ws = (char*)d_ws;
    unsigned short* an = (unsigned short*)ws;                       // 4 MB
    unsigned short* rn = (unsigned short*)(ws + (size_t)4194304);   // 4 MB
    unsigned short* bits = (unsigned short*)(ws + (size_t)8388608); // 8 MB bitmask
    float4* part4 = (float4*)(ws + (size_t)16777216);               // 512 KB
    float2* bpart = (float2*)(ws + (size_t)17825792);               // 512 B

    nrm_rows_kernel<<<(S_ * (N_ + M_)) / 4, 256, 0, stream>>>(art, ref, an, rn);
    bitpack_kernel<<<4096, 256, 0, stream>>>((const unsigned*)mask, bits);
    infonce_main_kernel<<<S_ * (N_ / 32) * CH_, 256, 0, stream>>>(
        an, rn, (const unsigned*)bits, lt, part4);
    reduce_kernel<<<(S_ * N_) / 256, 256, 0, stream>>>(part4, bpart);
    finalize_kernel<<<1, 64, 0, stream>>>(bpart, out);
}

// Round 7
// 409.907 us; speedup vs baseline: 1.2853x; 1.0498x over previous
//
#include <hip/hip_runtime.h>
#include <hip/hip_bf16.h>
#include <math.h>

#define S_ 4
#define N_ 4096
#define M_ 4096
#define D_ 128
#define NEG_ (-1e30f)
#define CH_ 2              // m-chunks per stem
#define MCH_ (M_ / CH_)    // 2048 m per chunk
#define NST_ (MCH_ / 64)   // 32 stages of 64 m
#define LN2_ 0.69314718055994531f
#define LOG2E_ 1.44269504088896340f

typedef __bf16 bf16x8 __attribute__((ext_vector_type(8)));
typedef float f32x4 __attribute__((ext_vector_type(4)));

// async global->LDS, 16B per lane (dest = wave-uniform base + lane*16)
__device__ __forceinline__ void gll16(const void* g, void* l) {
    __builtin_amdgcn_global_load_lds(
        (const __attribute__((address_space(1))) unsigned int*)g,
        (__attribute__((address_space(3))) unsigned int*)l, 16, 0, 0);
}

// RNE float -> bf16 bits
__device__ __forceinline__ unsigned short f2bf(float f) {
    unsigned u = __float_as_uint(f);
    unsigned r = (u + 0x7FFFu + ((u >> 16) & 1u)) >> 16;
    return (unsigned short)r;
}

// ---------------- Phase 1: L2-normalize art AND ref rows, write bf16 ----------------
__global__ void nrm_rows_kernel(const float* __restrict__ art, const float* __restrict__ ref,
                                unsigned short* __restrict__ an, unsigned short* __restrict__ rn) {
    const int w = threadIdx.x >> 6;
    const int lane = threadIdx.x & 63;
    const int row = blockIdx.x * 4 + w;             // 0 .. S_*(N_+M_)-1
    const bool is_art = row < S_ * N_;
    const float* src = is_art ? (art + (size_t)row * D_)
                              : (ref + (size_t)(row - S_ * N_) * D_);
    unsigned short* dst = is_art ? (an + (size_t)row * D_)
                                 : (rn + (size_t)(row - S_ * N_) * D_);
    const float2 v = *reinterpret_cast<const float2*>(src + lane * 2);
    float ss = v.x * v.x + v.y * v.y;
#pragma unroll
    for (int off = 1; off < 64; off <<= 1) ss += __shfl_xor(ss, off);
    const float scale = 1.0f / fmaxf(sqrtf(ss), 1e-12f);
    unsigned pack = (unsigned)f2bf(v.x * scale) | ((unsigned)f2bf(v.y * scale) << 16);
    *reinterpret_cast<unsigned*>(dst + lane * 2) = pack;
}

// ---------------- Phase 2: LDS-staged GEMM + fused mask stream + online LSE ----------------
// 1024 blocks (CH_ x S_ x 128 n-blocks) x 4 waves = 1 generation at 4 blocks/CU.
// Block: 32 anchors x 2048 m. Per 64-m stage:
//   - rn tile (16 KB) via global_load_lds dwordx4, double-buffered, XOR chunk-swizzle
//     applied on the GLOBAL source address (LDS dest linear); ds_read applies same XOR.
//   - mask tile read DIRECTLY from the raw input: 1 byte/lane/row (low byte of an int32
//     bool == its value, so stride 4 = int mode, stride 1 = byte mode — one code path),
//     packed to 64-bit row-words via __ballot, double-buffered in LDS (issued at stage
//     top for st+1, balloted at stage bottom -> full stage to hide HBM latency).
// Wave w: nsub=w&1 (16 anchors), msub=w>>1 (32 of 64 staged rows = 2 MFMA tiles).
__global__ __launch_bounds__(256, 4) void infonce_main_kernel(
    const unsigned short* __restrict__ an, const unsigned short* __restrict__ rn,
    const unsigned char* __restrict__ maskb, const float* __restrict__ logtemp,
    float4* __restrict__ part4) {

    const int bid = blockIdx.x;
    const int swz = (bid & 7) * 128 + (bid >> 3);   // 1024 % 8 == 0 -> bijective
    const int ch = swz >> 9;                        // 0..1
    const int s = (swz >> 7) & 3;                   // 0..3
    const int nblk = swz & 127;                     // 0..127
    const int n_base = nblk * 32;

    const int tid = threadIdx.x;
    const int w = tid >> 6;
    const int lane = tid & 63;
    const int nsub = w & 1;
    const int msub = w >> 1;
    const int n16 = n_base + nsub * 16;
    const int lrow = lane & 15;        // anchor col within 16-group
    const int lgrp = lane >> 4;        // k-group / m-row group
    const float scale2 = __expf(-logtemp[0]) * LOG2E_;   // 1/(temp*ln2)

    // mask dtype detection over 1 KB: byte-packed bools seen as u32 show values > 1
    const unsigned* mu = (const unsigned*)maskb;
    unsigned pr = 0;
#pragma unroll
    for (int i = 0; i < 4; ++i) pr |= (mu[i * 64 + lane] > 1u) ? 1u : 0u;
    const bool byte_mode = (__ballot(pr != 0) != 0ull);
    const size_t mstride = byte_mode ? 1 : 4;

    __shared__ unsigned char smem[2][64 * 256];     // 2 x 16 KB rn stage buffers
    __shared__ unsigned long long mbuf[2][32];      // 2 x 32 row-bitwords
    __shared__ float4 lds4[4][16];

    // anchor fragments resident in registers
    bf16x8 bfr[4];
    const unsigned short* abase = an + ((size_t)(s * N_ + n16 + lrow)) * D_ + lgrp * 8;
#pragma unroll
    for (int kc = 0; kc < 4; ++kc)
        bfr[kc] = *reinterpret_cast<const bf16x8*>(abase + kc * 32);

    // rn staging: thread covers row srow (+j*16), 16B chunk (lane&15), source XOR-swizzled
    const int srow = w * 4 + (lane >> 4);           // 0..15
    const int schunk = (lane & 15) ^ (srow & 7);
    const int lane_src_off = srow * 256 + schunk * 16;
    const unsigned char* rn_chunk =
        (const unsigned char*)(rn + ((size_t)(s * M_ + ch * MCH_)) * D_);

    // mask row byte-bases for this wave's 8 rows (anchors n_base + w*8 + r)
    size_t rowb[8];
#pragma unroll
    for (int r = 0; r < 8; ++r)
        rowb[r] = ((size_t)(s * N_ + n_base + w * 8 + r) * M_ + (size_t)ch * MCH_) * mstride;

    // ds_read addressing: row = msub*32 + t*16 + lrow, chunk = (kc*4+lgrp) ^ (lrow&7)
    const int rb0 = (msub * 32 + lrow) * 256;
    int coff[4];
#pragma unroll
    for (int kc = 0; kc < 4; ++kc) coff[kc] = ((kc * 4 + lgrp) ^ (lrow & 7)) * 16;

    float dmax = NEG_, dsum = 0.f, nsum = 0.f;
    int npos = 0;

    // prologue: rn stage 0 + mask stage 0
    {
        const unsigned char* src = rn_chunk + lane_src_off;
        unsigned char* dst = &smem[0][w * 1024];
#pragma unroll
        for (int j = 0; j < 4; ++j) gll16(src + j * 4096, dst + j * 4096);
        unsigned char mv[8];
        const size_t eoff = (size_t)lane * mstride;
#pragma unroll
        for (int r = 0; r < 8; ++r) mv[r] = maskb[rowb[r] + eoff];
        unsigned long long bl[8];
#pragma unroll
        for (int r = 0; r < 8; ++r) bl[r] = __ballot(mv[r] != 0);
        if (lane == 0) {
#pragma unroll
            for (int r = 0; r < 8; ++r) mbuf[0][w * 8 + r] = bl[r];
        }
    }
    __syncthreads();

    for (int st = 0; st < NST_; ++st) {
        const int nb = st & 1;
        const bool pf = (st + 1 < NST_);
        unsigned char mv[8];
        if (pf) {
            // rn prefetch into other buffer (async)
            const unsigned char* src = rn_chunk + (size_t)(st + 1) * 16384 + lane_src_off;
            unsigned char* dst = &smem[nb ^ 1][w * 1024];
#pragma unroll
            for (int j = 0; j < 4; ++j) gll16(src + j * 4096, dst + j * 4096);
            // mask loads for st+1 (consumed at stage bottom -> full stage of latency hiding)
            const size_t eoff = (size_t)((st + 1) * 64 + lane) * mstride;
#pragma unroll
            for (int r = 0; r < 8; ++r) mv[r] = maskb[rowb[r] + eoff];
        }
        // ---- 2 MFMA tiles from LDS ----
        const unsigned char* base = &smem[nb][0] + rb0;
        f32x4 acc0 = {0.f, 0.f, 0.f, 0.f}, acc1 = {0.f, 0.f, 0.f, 0.f};
#pragma unroll
        for (int kc = 0; kc < 4; ++kc) {
            acc0 = __builtin_amdgcn_mfma_f32_16x16x32_bf16(
                *reinterpret_cast<const bf16x8*>(base + coff[kc]), bfr[kc], acc0, 0, 0, 0);
            acc1 = __builtin_amdgcn_mfma_f32_16x16x32_bf16(
                *reinterpret_cast<const bf16x8*>(base + 4096 + coff[kc]), bfr[kc], acc1, 0, 0, 0);
        }
        // ---- epilogue: 8 logits (2 tiles x 4 m), bits from mbuf[nb] ----
        const unsigned long long wmask = mbuf[nb][nsub * 16 + lrow];
        const unsigned nib0 = (unsigned)(wmask >> (msub * 32 + lgrp * 4)) & 0xFu;
        const unsigned nib1 = (unsigned)(wmask >> (msub * 32 + 16 + lgrp * 4)) & 0xFu;
        float l0 = acc0[0] * scale2, l1 = acc0[1] * scale2, l2 = acc0[2] * scale2, l3 = acc0[3] * scale2;
        float l4 = acc1[0] * scale2, l5 = acc1[1] * scale2, l6 = acc1[2] * scale2, l7 = acc1[3] * scale2;
        float tmax = fmaxf(fmaxf(fmaxf(l0, l1), fmaxf(l2, l3)),
                           fmaxf(fmaxf(l4, l5), fmaxf(l6, l7)));
        const float nmx = fmaxf(dmax, tmax);
        const float r = exp2f(dmax - nmx);
        float e0 = exp2f(l0 - nmx), e1 = exp2f(l1 - nmx), e2 = exp2f(l2 - nmx), e3 = exp2f(l3 - nmx);
        float e4 = exp2f(l4 - nmx), e5 = exp2f(l5 - nmx), e6 = exp2f(l6 - nmx), e7 = exp2f(l7 - nmx);
        dsum = dsum * r + (((e0 + e1) + (e2 + e3)) + ((e4 + e5) + (e6 + e7)));
        float p0 = ((nib0 & 1u) ? e0 : 0.f) + (((nib0 >> 1) & 1u) ? e1 : 0.f);
        float p1 = (((nib0 >> 2) & 1u) ? e2 : 0.f) + (((nib0 >> 3) & 1u) ? e3 : 0.f);
        float p2 = ((nib1 & 1u) ? e4 : 0.f) + (((nib1 >> 1) & 1u) ? e5 : 0.f);
        float p3 = (((nib1 >> 2) & 1u) ? e6 : 0.f) + (((nib1 >> 3) & 1u) ? e7 : 0.f);
        nsum = nsum * r + ((p0 + p1) + (p2 + p3));
        npos += __popc(nib0 | (nib1 << 4));
        dmax = nmx;
        // ---- ballot + stash mask bits for st+1 ----
        if (pf) {
            unsigned long long bl[8];
#pragma unroll
            for (int r2 = 0; r2 < 8; ++r2) bl[r2] = __ballot(mv[r2] != 0);
            if (lane == 0) {
#pragma unroll
                for (int r2 = 0; r2 < 8; ++r2) mbuf[nb ^ 1][w * 8 + r2] = bl[r2];
            }
        }
        __syncthreads();
    }

    float npf = (float)npos;
    // merge the 4 lane-groups (same anchor, different m): xor 16, 32
#pragma unroll
    for (int off = 16; off < 64; off <<= 1) {
        float odm = __shfl_xor(dmax, off), ods = __shfl_xor(dsum, off);
        float ons = __shfl_xor(nsum, off), onp = __shfl_xor(npf, off);
        float nm = fmaxf(dmax, odm);
        float ra = exp2f(dmax - nm), rb = exp2f(odm - nm);
        dsum = dsum * ra + ods * rb;
        nsum = nsum * ra + ons * rb;
        npf += onp;
        dmax = nm;
    }

    if (lane < 16) lds4[w][lane] = make_float4(dmax, dsum, nsum, npf);
    __syncthreads();

    // merge msub halves (waves {0,2},{1,3}); write (anchor, chunk) partial
    if (w == 0 && lane < 32) {
        const int wsub = lane >> 4;
        const int ni = lane & 15;
        const float4 A = lds4[wsub][ni];
        const float4 B = lds4[wsub + 2][ni];
        const float nm = fmaxf(A.x, B.x);
        const float ra = exp2f(A.x - nm), rb = exp2f(B.x - nm);
        const float ds = A.y * ra + B.y * rb;
        const float ns = A.z * ra + B.z * rb;
        const float np = A.w + B.w;
        const int ag = s * N_ + n_base + wsub * 16 + ni;
        part4[ag * CH_ + ch] = make_float4(nm, ds, ns, np);
    }
}

// ---------------- Phase 3: merge chunk partials -> per-block (pa,cnt) partial ----------------
__global__ void reduce_kernel(const float4* __restrict__ part4, float2* __restrict__ bpart) {
    const int a = blockIdx.x * 256 + threadIdx.x;   // anchor
    const int w = threadIdx.x >> 6;
    const int lane = threadIdx.x & 63;
    float dm = NEG_, ds = 0.f, ns = 0.f, npf = 0.f;
#pragma unroll
    for (int ch = 0; ch < CH_; ++ch) {
        const float4 p = part4[a * CH_ + ch];
        const float m2 = fmaxf(dm, p.x);
        const float ra = exp2f(dm - m2), rb = exp2f(p.x - m2);
        ds = ds * ra + p.y * rb;
        ns = ns * ra + p.z * rb;
        npf += p.w;
        dm = m2;
    }
    const bool valid = (npf > 0.5f) && (npf < (float)M_ - 0.5f);
    float pa = valid ? LN2_ * (log2f(ds) - log2f(ns)) : 0.f;
    float cv = valid ? 1.f : 0.f;
#pragma unroll
    for (int off = 1; off < 64; off <<= 1) {
        pa += __shfl_xor(pa, off);
        cv += __shfl_xor(cv, off);
    }
    __shared__ float sp[4], sc[4];
    if (lane == 0) { sp[w] = pa; sc[w] = cv; }
    __syncthreads();
    if (threadIdx.x == 0)
        bpart[blockIdx.x] = make_float2(sp[0] + sp[1] + sp[2] + sp[3],
                                        sc[0] + sc[1] + sc[2] + sc[3]);
}

// ---------------- Phase 4: finalize (64 block-partials, 16 per stem) ----------------
__global__ void finalize_kernel(const float2* __restrict__ bpart, float* __restrict__ out) {
    const int t = threadIdx.x;   // 64 threads
    const float2 v = bpart[t];
    float pa = v.x, cv = v.y;
#pragma unroll
    for (int off = 1; off < 16; off <<= 1) {
        pa += __shfl_xor(pa, off);
        cv += __shfl_xor(cv, off);
    }
    const float p0 = __shfl(pa, 0),  c0 = __shfl(cv, 0);
    const float p1 = __shfl(pa, 16), c1 = __shfl(cv, 16);
    const float p2 = __shfl(pa, 32), c2 = __shfl(cv, 32);
    const float p3 = __shfl(pa, 48), c3 = __shfl(cv, 48);
    if (t == 0) {
        float total = 0.f;
        int scnt = 0;
        const float ps[4] = {p0, p1, p2, p3};
        const float cs[4] = {c0, c1, c2, c3};
        for (int s = 0; s < S_; ++s) {
            const float stem = ps[s] / fmaxf(cs[s], 1.f);
            if (cs[s] > 0.f) { total += stem; scnt++; }
        }
        out[0] = total / (float)(scnt > 0 ? scnt : 1);
    }
}

extern "C" void kernel_launch(void* const* d_in, const int* in_sizes, int n_in,
                              void* d_out, int out_size, void* d_ws, size_t ws_size,
                              hipStream_t stream) {
    const float* art = (const float*)d_in[0];
    const float* ref = (const float*)d_in[1];
    const unsigned char* mask = (const unsigned char*)d_in[2];
    const float* lt = (const float*)d_in[3];
    float* out = (float*)d_out;

    char* ws = (char*)d_ws;
    unsigned short* an = (unsigned short*)ws;                       // 4 MB
    unsigned short* rn = (unsigned short*)(ws + (size_t)4194304);   // 4 MB
    float4* part4 = (float4*)(ws + (size_t)8388608);                // 512 KB
    float2* bpart = (float2*)(ws + (size_t)9437184);                // 512 B

    nrm_rows_kernel<<<(S_ * (N_ + M_)) / 4, 256, 0, stream>>>(art, ref, an, rn);
    infonce_main_kernel<<<S_ * (N_ / 32) * CH_, 256, 0, stream>>>(an, rn, mask, lt, part4);
    reduce_kernel<<<(S_ * N_) / 256, 256, 0, stream>>>(part4, bpart);
    finalize_kernel<<<1, 64, 0, stream>>>(bpart, out);
}